// Round 14
// baseline (111.163 us; speedup 1.0000x reference)
//
#include <hip/hip_runtime.h>

// ---------------------------------------------------------------------------
// KAN forward as one bf16 MFMA GEMM:
//   y[n,o] = sum_i ( silu(x[n,i])*scale_base[o,i]
//                  + sum_b basis_b(x[n,i]) * scale_sp[o,i]*coef[o,i,b] ) + bias[o]
// A[n, i*8+s], W[o, i*8+s]: s=0 -> (silu, scale_base); s=1..6 -> (basis, sp*coef);
// s=7 -> zero pad.  K = 512*8 = 4096.
// Round 14: PRODUCER/CONSUMER WAVE SPECIALIZATION. 12 waves/block (768 thr):
// waves 0-7 consume (B->reg dbuf from L2, A-frag ds_read, 32 MFMA/kt, C-write),
// waves 8-11 produce (register-built acts -> LDS A rings). Each SIMD holds
// 2 consumer + 1 producer wave -> act-VALU issues under the matrix pipe
// structurally (no phase lock possible). BM=64 x BN=512, grid 256 (1 blk/CU),
// acts computed exactly once chip-wide. Raw s_barrier + lgkmcnt(0) only.
// ---------------------------------------------------------------------------

typedef short        bf16x8 __attribute__((ext_vector_type(8)));
typedef float        f32x4  __attribute__((ext_vector_type(4)));
typedef unsigned int u32x4  __attribute__((ext_vector_type(4)));

#define NROWS 16384
#define DIN   512
#define DOUT  512
#define BM    64
#define BN    512
#define NKT   64              // K-steps; each covers 8 input features

__device__ __forceinline__ unsigned short f2bf(float f) {
    unsigned int u = __float_as_uint(f);
    u += 0x7fffu + ((u >> 16) & 1u);          // round-to-nearest-even
    return (unsigned short)(u >> 16);
}

// ---------------------------------------------------------------------------
// Register-built activation: 8 bf16 slots [silu, basis0..5, pad] for one x.
// Cell-local: S = 1.5x+4.5, j = floor(S), t = S-j; cardinal cubics n0..n3 land
// at slots j-2..j+1. Placement in registers (parity + word-base cndmask),
// silu into slot 0, one ds_write_b128. Out-of-range -> zeros / pad slot.
// ---------------------------------------------------------------------------
__device__ __forceinline__ void kan_act_store(float xv, char* p16) {
    float S  = __builtin_fmaf(xv, 1.5f, 4.5f);
    float jf = floorf(S);
    float t  = S - jf;
    int   j  = (int)jf;
    float t2 = t * t;
    float t3 = t2 * t;
    float omt  = 1.0f - t;
    float omt2 = omt * omt;
    float n0 = omt2 * omt * (1.0f / 6.0f);                    // (1-t)^3/6
    float n1 = __builtin_fmaf(t3, 0.5f, -t2) + (2.0f / 3.0f); // (3t^3-6t^2+4)/6
    float u  = (t + t2) - t3;
    float n2 = __builtin_fmaf(u, 0.5f, 1.0f / 6.0f);          // (-3t^3+3t^2+3t+1)/6
    float n3 = t3 * (1.0f / 6.0f);                            // t^3/6
    float e  = __expf(-xv);
    float si = xv * __builtin_amdgcn_rcpf(1.0f + e);          // silu

    unsigned P01, P23, WS;
    asm("v_cvt_pk_bf16_f32 %0, %1, %2" : "=v"(P01) : "v"(n0), "v"(n1));
    asm("v_cvt_pk_bf16_f32 %0, %1, %2" : "=v"(P23) : "v"(n2), "v"(n3));
    asm("v_cvt_pk_bf16_f32 %0, %1, %2" : "=v"(WS)  : "v"(si), "v"(0.0f));
    unsigned U = P01 << 16;                      // (0 , n0)
    unsigned V = (P01 >> 16) | (P23 << 16);      // (n1, n2)
    unsigned Z = P23 >> 16;                      // (n3, 0 )
    bool odd = (j & 1) != 0;
    unsigned c0 = odd ? U : P01;
    unsigned c1 = odd ? V : P23;
    unsigned c2 = odd ? Z : 0u;
    int b = (j - 2) >> 1;                        // arithmetic shift (floor)
    u32x4 w;
    w[0] = (b == 0) ? c0 : (b == -1) ? c1 : (b == -2) ? c2 : 0u;
    w[1] = (b == 1) ? c0 : (b ==  0) ? c1 : (b == -1) ? c2 : 0u;
    w[2] = (b == 2) ? c0 : (b ==  1) ? c1 : (b ==  0) ? c2 : 0u;
    w[3] = (b == 3) ? c0 : (b ==  2) ? c1 : (b ==  1) ? c2 : 0u;
    w[0] = (w[0] & 0xFFFF0000u) | (WS & 0xFFFFu);   // silu -> slot 0
    *(u32x4*)p16 = w;
}

// ---------------------------------------------------------------------------
// Prep: pack W into ws as bf16 16B slot-groups, coalesced for the GEMM:
//   byte = ((kt*2 + ks)*512 + o)*64 + fg*16      (i = kt*8 + ks*4 + fg)
// One 4MB region; per (kt,ks) slice = 32 KB (L2/L1-hot: all blocks in step).
// ---------------------------------------------------------------------------
__global__ __launch_bounds__(256) void kan_prep(
    const float* __restrict__ coef, const float* __restrict__ scale_base,
    const float* __restrict__ scale_sp, unsigned short* __restrict__ wt)
{
    int t = blockIdx.x * 256 + threadIdx.x;   // t = o*512 + i
    int o = t >> 9;
    int i = t & 511;
    float sb = scale_base[t];
    float sp = scale_sp[t];
    const float* cp = coef + (size_t)t * 6;
    bf16x8 w;
    w[0] = (short)f2bf(sb);
#pragma unroll
    for (int b = 0; b < 6; ++b) w[1 + b] = (short)f2bf(sp * cp[b]);
    w[7] = 0;
    int kt = i >> 3, s = i & 7, ks = s >> 2, fg = s & 3;
    size_t off = ((size_t)((kt * 2 + ks) * 512 + o)) * 64 + fg * 16;
    *(bf16x8*)((char*)wt + off) = w;
}

// ---------------------------------------------------------------------------
// Fused GEMM, wave-specialized. Consumers (waves 0-7): wave tile 64x64 at
// col0 = wid*64; B from L2 to regs (named dbuf); A-frags from LDS ring.
// Producers (waves 8-11): 2 acts/thread/kt into ring[(kt+1)&1].
// One s_barrier per kt (both roles), lgkmcnt(0) only - B loads cross barriers.
// ---------------------------------------------------------------------------
__global__ __launch_bounds__(768, 3) void kan_gemm(
    const float* __restrict__ x, const unsigned short* __restrict__ wt,
    const float* __restrict__ bias, float* __restrict__ y)
{
    __shared__ char As[2][BM * 128];   // 2 x 8 KB, swizzled rows of 64 bf16

    const int tid  = threadIdx.x;
    const int lane = tid & 63;
    const int wid  = tid >> 6;        // 0..11

    // bijective XCD-aware swizzle: 256 wgs, 8 XCDs, contiguous 32-chunk each.
    int bid = blockIdx.x;
    int mt  = (bid & 7) * 32 + (bid >> 3);    // 0..255
    const int row0 = mt * BM;

    const int fr = lane & 15;         // fragment row/col
    const int fg = lane >> 4;         // k-group 0..3

    if (wid < 8) {
        // ================= CONSUMER: pure GEMM =================
        // B-frag bases: frag (ks, n2) at iter kt reads 16B from
        //   wt + (kt*2+ks)*32768 + colpart[n2],
        //   colpart = (wid*64+n2*16+fr)*64 + fg*16  -> 1KB contiguous per wave.
        const char* wb = (const char*)wt;
        int colpart[4];
#pragma unroll
        for (int n2 = 0; n2 < 4; ++n2)
            colpart[n2] = (wid * 64 + n2 * 16 + fr) * 64 + fg * 16;

#define LOADB(B, ktv)                                                         \
    {                                                                         \
        _Pragma("unroll")                                                     \
        for (int q = 0; q < 8; ++q) {                                         \
            int n2_ = q & 3, ks_ = q >> 2;                                    \
            B[q] = *(const bf16x8*)(wb + (size_t)((ktv) * 2 + ks_) * 32768    \
                                    + colpart[n2_]);                          \
        }                                                                     \
    }

        f32x4 acc[4][4];
#pragma unroll
        for (int m2 = 0; m2 < 4; ++m2)
#pragma unroll
            for (int n2 = 0; n2 < 4; ++n2) {
                f32x4 z = {0.f, 0.f, 0.f, 0.f};
                acc[m2][n2] = z;
            }

        bf16x8 Ba[8], Bb[8];
        LOADB(Ba, 0);
        __builtin_amdgcn_s_barrier();     // matches producer prologue barrier

// consume Bcur + As[ktv&1]; prefetch Bnext for ktv+1.
#define CSTEP(ktv, Bcur, Bnext)                                               \
    {                                                                         \
        const int cur_ = (ktv) & 1;                                           \
        bf16x8 af_[2][4];                                                     \
        _Pragma("unroll")                                                     \
        for (int ks_ = 0; ks_ < 2; ++ks_) {                                   \
            _Pragma("unroll")                                                 \
            for (int m2_ = 0; m2_ < 4; ++m2_) {                               \
                int rr_ = m2_ * 16 + fr;                                      \
                af_[ks_][m2_] = *(const bf16x8*)(&As[cur_][0] + rr_ * 128     \
                    + ((ks_ * 64 + fg * 16) ^ ((rr_ & 7) << 4)));             \
            }                                                                 \
        }                                                                     \
        if ((ktv) + 1 < NKT) LOADB(Bnext, (ktv) + 1);                         \
        _Pragma("unroll")                                                     \
        for (int ks_ = 0; ks_ < 2; ++ks_)                                     \
            _Pragma("unroll")                                                 \
            for (int m2_ = 0; m2_ < 4; ++m2_)                                 \
                _Pragma("unroll")                                             \
                for (int n2_ = 0; n2_ < 4; ++n2_)                             \
                    acc[m2_][n2_] = __builtin_amdgcn_mfma_f32_16x16x32_bf16(  \
                        af_[ks_][m2_], Bcur[ks_ * 4 + n2_], acc[m2_][n2_],    \
                        0, 0, 0);                                             \
        asm volatile("s_waitcnt lgkmcnt(0)" ::: "memory");                    \
        __builtin_amdgcn_s_barrier();                                         \
    }

        for (int kt = 0; kt < NKT; kt += 2) {
            CSTEP(kt, Ba, Bb);
            CSTEP(kt + 1, Bb, Ba);
        }

        // ---- epilogue: C/D layout col = lane&15, row = (lane>>4)*4 + reg
        const int orow0 = row0 + fg * 4;
        const int ocol0 = wid * 64 + fr;
#pragma unroll
        for (int n2 = 0; n2 < 4; ++n2) {
            float bv = bias[ocol0 + n2 * 16];
#pragma unroll
            for (int m2 = 0; m2 < 4; ++m2) {
#pragma unroll
                for (int r = 0; r < 4; ++r) {
                    y[(size_t)(orow0 + m2 * 16 + r) * DOUT + (ocol0 + n2 * 16)]
                        = acc[m2][n2][r] + bv;
                }
            }
        }
#undef CSTEP
#undef LOADB
    } else {
        // ================= PRODUCER: acts -> LDS rings =================
        const int ptid = tid - 512;       // 0..255
        const int ar = ptid >> 2;         // 0..63
        const int ap = ptid & 3;          // 0..3 (features 2ap, 2ap+1)
        const float* xp = x + (size_t)(row0 + ar) * DIN + ap * 2;
        const int as_sw = (ar & 7) << 4;
        const int c0 = (ap * 2) << 4;
        char* const arow0 = &As[0][ar * 128];
        char* const arow1 = &As[1][ar * 128];

        // prologue: acts(kt=0) -> As[0]
        {
            float2 xa = *(const float2*)(xp);
            kan_act_store(xa.x, arow0 + (c0 ^ as_sw));
            kan_act_store(xa.y, arow0 + ((c0 + 16) ^ as_sw));
        }
        float2 xb = *(const float2*)(xp + 8);   // x for kt=1
        asm volatile("s_waitcnt lgkmcnt(0)" ::: "memory");
        __builtin_amdgcn_s_barrier();

        for (int kt = 0; kt < NKT; ++kt) {
            if (kt + 1 < NKT) {
                char* rowp = ((kt + 1) & 1) ? arow1 : arow0;
                kan_act_store(xb.x, rowp + (c0 ^ as_sw));
                kan_act_store(xb.y, rowp + ((c0 + 16) ^ as_sw));
                if (kt + 2 < NKT)
                    xb = *(const float2*)(xp + (kt + 2) * 8);
            }
            asm volatile("s_waitcnt lgkmcnt(0)" ::: "memory");
            __builtin_amdgcn_s_barrier();
        }
    }
}

extern "C" void kernel_launch(void* const* d_in, const int* in_sizes, int n_in,
                              void* d_out, int out_size, void* d_ws, size_t ws_size,
                              hipStream_t stream)
{
    const float* x          = (const float*)d_in[0];
    const float* coef       = (const float*)d_in[1];
    const float* scale_base = (const float*)d_in[2];
    const float* scale_sp   = (const float*)d_in[3];
    const float* bias       = (const float*)d_in[4];
    unsigned short* wt = (unsigned short*)d_ws;   // 4 MB packed wt[kt][ks][o][fg]
    float* y = (float*)d_out;

    kan_prep<<<1024, 256, 0, stream>>>(coef, scale_base, scale_sp, wt);
    kan_gemm<<<256, 768, 0, stream>>>(x, wt, bias, y);
}

// Round 15
// 86.610 us; speedup vs baseline: 1.2835x; 1.2835x over previous
//
#include <hip/hip_runtime.h>

// ---------------------------------------------------------------------------
// KAN forward as one bf16 MFMA GEMM:
//   y[n,o] = sum_i ( silu(x[n,i])*scale_base[o,i]
//                  + sum_b basis_b(x[n,i]) * scale_sp[o,i]*coef[o,i,b] ) + bias[o]
// A[n, i*8+s], W[o, i*8+s]: s=0 -> (silu, scale_base); s=1..6 -> (basis, sp*coef);
// s=7 -> zero pad.  K = 512*8 = 4096.
// Round 15: decouple ds_read from MFMA. Acts produced 2 kt ahead into a
// depth-4 LDS ring; A-frags for kt+1 are register-prefetched DURING kt's MFMA
// (slot kt+1 valid since kt-1's barrier), so MFMA(kt) is register-only and the
// LDS latency chain (barrier -> ds_read -> MFMA, ~120+ cyc x 64) vanishes.
// BN=512 (acts once chip-wide, VALU pipe halved), BM=64, 512 thr = 8 waves,
// 1 blk/CU, B named-dbuf from L2 (coalesced wt layout), per-kt lgkmcnt(0) +
// raw s_barrier (vmcnt never drained; B loads cross barriers).
// ---------------------------------------------------------------------------

typedef short        bf16x8 __attribute__((ext_vector_type(8)));
typedef float        f32x4  __attribute__((ext_vector_type(4)));
typedef unsigned int u32x4  __attribute__((ext_vector_type(4)));

#define NROWS 16384
#define DIN   512
#define DOUT  512
#define BM    64
#define BN    512
#define NKT   64              // K-steps; each covers 8 input features

__device__ __forceinline__ unsigned short f2bf(float f) {
    unsigned int u = __float_as_uint(f);
    u += 0x7fffu + ((u >> 16) & 1u);          // round-to-nearest-even
    return (unsigned short)(u >> 16);
}

// ---------------------------------------------------------------------------
// Register-built activation: 8 bf16 slots [silu, basis0..5, pad] for one x.
// Cell-local: S = 1.5x+4.5, j = floor(S), t = S-j; cardinal cubics n0..n3 land
// at slots j-2..j+1. Placement in registers (parity + word-base cndmask),
// silu into slot 0, one ds_write_b128. Out-of-range -> zeros / pad slot.
// ---------------------------------------------------------------------------
__device__ __forceinline__ void kan_act_store(float xv, char* p16) {
    float S  = __builtin_fmaf(xv, 1.5f, 4.5f);
    float jf = floorf(S);
    float t  = S - jf;
    int   j  = (int)jf;
    float t2 = t * t;
    float t3 = t2 * t;
    float omt  = 1.0f - t;
    float omt2 = omt * omt;
    float n0 = omt2 * omt * (1.0f / 6.0f);                    // (1-t)^3/6
    float n1 = __builtin_fmaf(t3, 0.5f, -t2) + (2.0f / 3.0f); // (3t^3-6t^2+4)/6
    float u  = (t + t2) - t3;
    float n2 = __builtin_fmaf(u, 0.5f, 1.0f / 6.0f);          // (-3t^3+3t^2+3t+1)/6
    float n3 = t3 * (1.0f / 6.0f);                            // t^3/6
    float e  = __expf(-xv);
    float si = xv * __builtin_amdgcn_rcpf(1.0f + e);          // silu

    unsigned P01, P23, WS;
    asm("v_cvt_pk_bf16_f32 %0, %1, %2" : "=v"(P01) : "v"(n0), "v"(n1));
    asm("v_cvt_pk_bf16_f32 %0, %1, %2" : "=v"(P23) : "v"(n2), "v"(n3));
    asm("v_cvt_pk_bf16_f32 %0, %1, %2" : "=v"(WS)  : "v"(si), "v"(0.0f));
    unsigned U = P01 << 16;                      // (0 , n0)
    unsigned V = (P01 >> 16) | (P23 << 16);      // (n1, n2)
    unsigned Z = P23 >> 16;                      // (n3, 0 )
    bool odd = (j & 1) != 0;
    unsigned c0 = odd ? U : P01;
    unsigned c1 = odd ? V : P23;
    unsigned c2 = odd ? Z : 0u;
    int b = (j - 2) >> 1;                        // arithmetic shift (floor)
    u32x4 w;
    w[0] = (b == 0) ? c0 : (b == -1) ? c1 : (b == -2) ? c2 : 0u;
    w[1] = (b == 1) ? c0 : (b ==  0) ? c1 : (b == -1) ? c2 : 0u;
    w[2] = (b == 2) ? c0 : (b ==  1) ? c1 : (b ==  0) ? c2 : 0u;
    w[3] = (b == 3) ? c0 : (b ==  2) ? c1 : (b ==  1) ? c2 : 0u;
    w[0] = (w[0] & 0xFFFF0000u) | (WS & 0xFFFFu);   // silu -> slot 0
    *(u32x4*)p16 = w;
}

// ---------------------------------------------------------------------------
// Prep: pack W into ws as bf16 16B slot-groups, coalesced for the GEMM:
//   byte = ((kt*2 + ks)*512 + o)*64 + fg*16      (i = kt*8 + ks*4 + fg)
// One 4MB region; per (kt,ks) slice = 32 KB, hot across all CUs in step.
// ---------------------------------------------------------------------------
__global__ __launch_bounds__(256) void kan_prep(
    const float* __restrict__ coef, const float* __restrict__ scale_base,
    const float* __restrict__ scale_sp, unsigned short* __restrict__ wt)
{
    int t = blockIdx.x * 256 + threadIdx.x;   // t = o*512 + i
    int o = t >> 9;
    int i = t & 511;
    float sb = scale_base[t];
    float sp = scale_sp[t];
    const float* cp = coef + (size_t)t * 6;
    bf16x8 w;
    w[0] = (short)f2bf(sb);
#pragma unroll
    for (int b = 0; b < 6; ++b) w[1 + b] = (short)f2bf(sp * cp[b]);
    w[7] = 0;
    int kt = i >> 3, s = i & 7, ks = s >> 2, fg = s & 3;
    size_t off = ((size_t)((kt * 2 + ks) * 512 + o)) * 64 + fg * 16;
    *(bf16x8*)((char*)wt + off) = w;
}

// ---------------------------------------------------------------------------
// Fused GEMM: BM=64 x BN=512, 512 threads (8 waves, wave tile 64x64 at
// col = wid*64). Depth-4 A ring; af register prefetch 1 kt ahead; acts 2 ahead.
// ---------------------------------------------------------------------------
__global__ __launch_bounds__(512, 2) void kan_gemm(
    const float* __restrict__ x, const unsigned short* __restrict__ wt,
    const float* __restrict__ bias, float* __restrict__ y)
{
    __shared__ char As[4][BM * 128];   // 4 x 8 KB ring, swizzled rows

    const int tid  = threadIdx.x;
    const int lane = tid & 63;
    const int wid  = tid >> 6;        // 0..7 (col slice)

    // bijective XCD-aware swizzle: 256 wgs, 8 XCDs, contiguous 32-chunk each.
    int bid = blockIdx.x;
    int mt  = (bid & 7) * 32 + (bid >> 3);    // 0..255
    const int row0 = mt * BM;

    // A staging: thread -> (row ar, feature ap); ONE act per thread per kt
    const int ar = tid >> 3;          // 0..63
    const int ap = tid & 7;           // 0..7
    const float* xp = x + (size_t)(row0 + ar) * DIN + ap;
    const int as_sw = (ar & 7) << 4;
    const int c0 = ap << 4;

    const int fr = lane & 15;         // fragment row/col
    const int fg = lane >> 4;         // k-group 0..3

    // B-frag bases: frag (ks, n2) at iter kt reads 16B from
    //   wt + (kt*2+ks)*32768 + colpart[n2],  colpart = (wid*64+n2*16+fr)*64+fg*16
    const char* wb = (const char*)wt;
    int colpart[4];
#pragma unroll
    for (int n2 = 0; n2 < 4; ++n2)
        colpart[n2] = (wid * 64 + n2 * 16 + fr) * 64 + fg * 16;

#define LOADB(B, ktv)                                                         \
    {                                                                         \
        _Pragma("unroll")                                                     \
        for (int q = 0; q < 8; ++q) {                                         \
            int n2_ = q & 3, ks_ = q >> 2;                                    \
            B[q] = *(const bf16x8*)(wb + (size_t)((ktv) * 2 + ks_) * 32768    \
                                    + colpart[n2_]);                          \
        }                                                                     \
    }

// read the 16 A-fragments of ring slot 'slot' into AF (af[ks*4+m2])
#define RD_AF(AF, slot)                                                       \
    {                                                                         \
        _Pragma("unroll")                                                     \
        for (int q = 0; q < 8; ++q) {                                         \
            int ks_ = q >> 2, m2_ = q & 3;                                    \
            int rr_ = m2_ * 16 + fr;                                          \
            AF[q] = *(const bf16x8*)(&As[slot][0] + rr_ * 128                 \
                + ((ks_ * 64 + fg * 16) ^ ((rr_ & 7) << 4)));                 \
        }                                                                     \
    }

    f32x4 acc[4][4];
#pragma unroll
    for (int m2 = 0; m2 < 4; ++m2)
#pragma unroll
        for (int n2 = 0; n2 < 4; ++n2) {
            f32x4 z = {0.f, 0.f, 0.f, 0.f};
            acc[m2][n2] = z;
        }

    bf16x8 Ba[8], Bb[8];      // B dbuf (8 frags = 2ks x 4n2)
    bf16x8 afA[8], afB[8];    // A-frag dbuf

    // ------------- prologue: acts(0)->r0, acts(1)->r1, B(0), af(0) ----------
    LOADB(Ba, 0);
    kan_act_store(xp[0], &As[0][ar * 128] + (c0 ^ as_sw));
    kan_act_store(xp[8], &As[1][ar * 128] + (c0 ^ as_sw));
    float xb = xp[16];                // x for acts(2)
    asm volatile("s_waitcnt lgkmcnt(0)" ::: "memory");
    __builtin_amdgcn_s_barrier();
    RD_AF(afA, 0);                    // frags for kt=0 (one-time exposed read)

// one K-step: MFMA(AFc,Bc) register-only; meanwhile load B(kt+1)->Bn,
// prefetch af(kt+1) from ring slot Rn1 (valid since kt-1's barrier), and
// produce acts(kt+2) into slot Rw (reused slot's reads finished 2 barriers
// ago). lgkmcnt(0)+barrier publishes the act writes; vmcnt never drained.
#define STEP(ktv, Rn1, Rw, AFc, AFn, Bc, Bn)                                  \
    {                                                                         \
        if ((ktv) + 1 < NKT) LOADB(Bn, (ktv) + 1);                            \
        if ((ktv) + 1 < NKT) RD_AF(AFn, Rn1);                                 \
        if ((ktv) + 2 < NKT) {                                                \
            kan_act_store(xb, &As[Rw][ar * 128] + (c0 ^ as_sw));              \
            if ((ktv) + 3 < NKT) xb = xp[((ktv) + 3) * 8];                    \
        }                                                                     \
        _Pragma("unroll")                                                     \
        for (int ks_ = 0; ks_ < 2; ++ks_)                                     \
            _Pragma("unroll")                                                 \
            for (int m2_ = 0; m2_ < 4; ++m2_)                                 \
                _Pragma("unroll")                                             \
                for (int n2_ = 0; n2_ < 4; ++n2_)                             \
                    acc[m2_][n2_] = __builtin_amdgcn_mfma_f32_16x16x32_bf16(  \
                        AFc[ks_ * 4 + m2_], Bc[ks_ * 4 + n2_], acc[m2_][n2_], \
                        0, 0, 0);                                             \
        if ((ktv) + 1 < NKT) {                                                \
            asm volatile("s_waitcnt lgkmcnt(0)" ::: "memory");                \
            __builtin_amdgcn_s_barrier();                                     \
        }                                                                     \
    }

    for (int kt = 0; kt < NKT; kt += 4) {
        STEP(kt,     1, 2, afA, afB, Ba, Bb);
        STEP(kt + 1, 2, 3, afB, afA, Bb, Ba);
        STEP(kt + 2, 3, 0, afA, afB, Ba, Bb);
        STEP(kt + 3, 0, 1, afB, afA, Bb, Ba);
    }

    // ---- epilogue: C/D layout col = lane&15, row = (lane>>4)*4 + reg
    const int orow0 = row0 + fg * 4;
    const int ocol0 = wid * 64 + fr;
#pragma unroll
    for (int n2 = 0; n2 < 4; ++n2) {
        float bv = bias[ocol0 + n2 * 16];
#pragma unroll
        for (int m2 = 0; m2 < 4; ++m2) {
#pragma unroll
            for (int r = 0; r < 4; ++r) {
                y[(size_t)(orow0 + m2 * 16 + r) * DOUT + (ocol0 + n2 * 16)]
                    = acc[m2][n2][r] + bv;
            }
        }
    }
#undef STEP
#undef RD_AF
#undef LOADB
}

extern "C" void kernel_launch(void* const* d_in, const int* in_sizes, int n_in,
                              void* d_out, int out_size, void* d_ws, size_t ws_size,
                              hipStream_t stream)
{
    const float* x          = (const float*)d_in[0];
    const float* coef       = (const float*)d_in[1];
    const float* scale_base = (const float*)d_in[2];
    const float* scale_sp   = (const float*)d_in[3];
    const float* bias       = (const float*)d_in[4];
    unsigned short* wt = (unsigned short*)d_ws;   // 4 MB packed wt[kt][ks][o][fg]
    float* y = (float*)d_out;

    kan_prep<<<1024, 256, 0, stream>>>(coef, scale_base, scale_sp, wt);
    kan_gemm<<<256, 512, 0, stream>>>(x, wt, bias, y);
}

// Round 16
// 78.876 us; speedup vs baseline: 1.4093x; 1.0981x over previous
//
#include <hip/hip_runtime.h>

// ---------------------------------------------------------------------------
// KAN forward as one bf16 MFMA GEMM:
//   y[n,o] = sum_i ( silu(x[n,i])*scale_base[o,i]
//                  + sum_b basis_b(x[n,i]) * scale_sp[o,i]*coef[o,i,b] ) + bias[o]
// A[n, i*8+s], W[o, i*8+s]: s=0 -> (silu, scale_base); s=1..6 -> (basis, sp*coef);
// s=7 -> zero pad.  K = 512*8 = 4096.
// Round 16: r15 geometry (BM=64/BN=512, acts once chip-wide, 8 waves, 1
// blk/CU) with the software pipeline FORCED via inline asm: all loop memory
// ops are volatile asm (global_load_dwordx4 B-prefetch, global_load_dword x,
// ds_read_b128 A-frags, ds_write_b128 act) with hand-counted
// s_waitcnt vmcnt(9)/lgkmcnt(1) (never vmcnt(0) in steady state) +
// sched_barrier(0) fences. Evidence: r15 VGPR=124 < 192 declared dbuf state -
// the compiler had collapsed the prefetch distance; asm pins it.
// ---------------------------------------------------------------------------

typedef short        bf16x8 __attribute__((ext_vector_type(8)));
typedef float        f32x4  __attribute__((ext_vector_type(4)));
typedef unsigned int u32x4  __attribute__((ext_vector_type(4)));

#define NROWS 16384
#define DIN   512
#define DOUT  512
#define BM    64
#define BN    512
#define NKT   64              // K-steps; each covers 8 input features

__device__ __forceinline__ unsigned short f2bf(float f) {
    unsigned int u = __float_as_uint(f);
    u += 0x7fffu + ((u >> 16) & 1u);          // round-to-nearest-even
    return (unsigned short)(u >> 16);
}

// ---------------------------------------------------------------------------
// Register-built activation: 8 bf16 slots [silu, basis0..5, pad] for one x,
// returned as u32x4 (caller stores with one ds_write_b128).
// ---------------------------------------------------------------------------
__device__ __forceinline__ u32x4 kan_act(float xv) {
    float S  = __builtin_fmaf(xv, 1.5f, 4.5f);
    float jf = floorf(S);
    float t  = S - jf;
    int   j  = (int)jf;
    float t2 = t * t;
    float t3 = t2 * t;
    float omt  = 1.0f - t;
    float omt2 = omt * omt;
    float n0 = omt2 * omt * (1.0f / 6.0f);                    // (1-t)^3/6
    float n1 = __builtin_fmaf(t3, 0.5f, -t2) + (2.0f / 3.0f); // (3t^3-6t^2+4)/6
    float u  = (t + t2) - t3;
    float n2 = __builtin_fmaf(u, 0.5f, 1.0f / 6.0f);          // (-3t^3+3t^2+3t+1)/6
    float n3 = t3 * (1.0f / 6.0f);                            // t^3/6
    float e  = __expf(-xv);
    float si = xv * __builtin_amdgcn_rcpf(1.0f + e);          // silu

    unsigned P01, P23, WS;
    asm("v_cvt_pk_bf16_f32 %0, %1, %2" : "=v"(P01) : "v"(n0), "v"(n1));
    asm("v_cvt_pk_bf16_f32 %0, %1, %2" : "=v"(P23) : "v"(n2), "v"(n3));
    asm("v_cvt_pk_bf16_f32 %0, %1, %2" : "=v"(WS)  : "v"(si), "v"(0.0f));
    unsigned U = P01 << 16;                      // (0 , n0)
    unsigned V = (P01 >> 16) | (P23 << 16);      // (n1, n2)
    unsigned Z = P23 >> 16;                      // (n3, 0 )
    bool odd = (j & 1) != 0;
    unsigned c0 = odd ? U : P01;
    unsigned c1 = odd ? V : P23;
    unsigned c2 = odd ? Z : 0u;
    int b = (j - 2) >> 1;                        // arithmetic shift (floor)
    u32x4 w;
    w[0] = (b == 0) ? c0 : (b == -1) ? c1 : (b == -2) ? c2 : 0u;
    w[1] = (b == 1) ? c0 : (b ==  0) ? c1 : (b == -1) ? c2 : 0u;
    w[2] = (b == 2) ? c0 : (b ==  1) ? c1 : (b ==  0) ? c2 : 0u;
    w[3] = (b == 3) ? c0 : (b ==  2) ? c1 : (b ==  1) ? c2 : 0u;
    w[0] = (w[0] & 0xFFFF0000u) | (WS & 0xFFFFu);   // silu -> slot 0
    return w;
}

// ---------------------------------------------------------------------------
// Prep: pack W as bf16 16B slot-groups, coalesced for the GEMM:
//   byte = ((kt*2 + ks)*512 + o)*64 + fg*16      (i = kt*8 + ks*4 + fg)
// ---------------------------------------------------------------------------
__global__ __launch_bounds__(256) void kan_prep(
    const float* __restrict__ coef, const float* __restrict__ scale_base,
    const float* __restrict__ scale_sp, unsigned short* __restrict__ wt)
{
    int t = blockIdx.x * 256 + threadIdx.x;   // t = o*512 + i
    int o = t >> 9;
    int i = t & 511;
    float sb = scale_base[t];
    float sp = scale_sp[t];
    const float* cp = coef + (size_t)t * 6;
    bf16x8 w;
    w[0] = (short)f2bf(sb);
#pragma unroll
    for (int b = 0; b < 6; ++b) w[1 + b] = (short)f2bf(sp * cp[b]);
    w[7] = 0;
    int kt = i >> 3, s = i & 7, ks = s >> 2, fg = s & 3;
    size_t off = ((size_t)((kt * 2 + ks) * 512 + o)) * 64 + fg * 16;
    *(bf16x8*)((char*)wt + off) = w;
}

// ---------------------------------------------------------------------------
// Fused GEMM: BM=64 x BN=512, 512 threads (8 waves, wave tile 64x64 at
// col = wid*64), asm-pinned software pipeline.
// ---------------------------------------------------------------------------
__global__ __launch_bounds__(512, 2) void kan_gemm(
    const float* __restrict__ x, const unsigned short* __restrict__ wt,
    const float* __restrict__ bias, float* __restrict__ y)
{
    __shared__ char As[2][BM * 128];   // 2 x 8 KB ring, swizzled rows

    const int tid  = threadIdx.x;
    const int lane = tid & 63;
    const int wid  = tid >> 6;        // 0..7 (col slice)

    // bijective XCD-aware swizzle: 256 wgs, 8 XCDs, contiguous 32-chunk each.
    int bid = blockIdx.x;
    int mt  = (bid & 7) * 32 + (bid >> 3);    // 0..255
    const int row0 = mt * BM;

    // A staging: thread -> (row ar, feature ap); ONE act per thread per kt
    const int ar = tid >> 3;          // 0..63
    const int ap = tid & 7;           // 0..7
    const float* xp = x + (size_t)(row0 + ar) * DIN + ap;
    const int as_sw = (ar & 7) << 4;
    const int c0 = ap << 4;

    const int fr = lane & 15;         // fragment row/col
    const int fg = lane >> 4;         // k-group 0..3

    // LDS byte offset of As base (addrspace(3) cast yields raw LDS offset)
    const unsigned asb =
        (unsigned)(unsigned long long)(__attribute__((address_space(3))) char*)&As[0][0];

    // B-frag per-thread base pointers: frag (ks, n2) at iter kt reads 16B at
    //   pB[n2] + kt*65536 + ks*32768,  pB[n2] = wt + (wid*64+n2*16+fr)*64+fg*16
    const char* pB[4];
#pragma unroll
    for (int n2 = 0; n2 < 4; ++n2)
        pB[n2] = (const char*)wt + (size_t)((wid * 64 + n2 * 16 + fr) * 64 + fg * 16);

    f32x4 acc[4][4];
#pragma unroll
    for (int m2 = 0; m2 < 4; ++m2)
#pragma unroll
        for (int n2 = 0; n2 < 4; ++n2) {
            f32x4 z = {0.f, 0.f, 0.f, 0.f};
            acc[m2][n2] = z;
        }

    bf16x8 Ba[8], Bb[8];
    float  xA, xB;

    // ---------------- prologue ----------------
    // act(0) -> slot 0 (plain x load; its conservative wait is one-time)
    {
        float x0 = xp[0];
        u32x4 w0 = kan_act(x0);
        unsigned woff = asb + ar * 128 + (c0 ^ as_sw);
        asm volatile("ds_write_b128 %0, %1" :: "v"(woff), "v"(w0));
    }
    // B(0) -> Ba, xA = x[8]; these 9 stay in flight into STEP(0)
#pragma unroll
    for (int q = 0; q < 8; ++q) {
        int n2_ = q & 3, ks_ = q >> 2;
        const void* a_ = pB[n2_] + ks_ * 32768;
        asm volatile("global_load_dwordx4 %0, %1, off" : "=&v"(Ba[q]) : "v"(a_));
    }
    asm volatile("global_load_dword %0, %1, off"
                 : "=&v"(xA) : "v"((const void*)(xp + 8)));
    asm volatile("s_waitcnt lgkmcnt(0)");
    __builtin_amdgcn_s_barrier();

// One K-step. Invariant at entry: 9 VMEM outstanding = [B(ktv) x8, x(ktv+1)].
// Issue AF ds_reads (8) + B(ktv+1) x8 + x(ktv+2) -> 18 outstanding ->
// vmcnt(9) drains the old 9 (B(ktv), xcur ready; new 9 in flight).
// act(ktv+1) VALU covers AF latency; lgkmcnt(1) = AF done, act write pending.
// MFMA register-only. lgkmcnt(0)+barrier publishes the act slot.
#define STEP(ktv, Bc, Bn, xcur, xnext)                                        \
    {                                                                         \
        const int cur_ = (ktv) & 1;                                           \
        const unsigned abase_ = asb + cur_ * 8192;                            \
        bf16x8 AF[8];                                                         \
        _Pragma("unroll")                                                     \
        for (int q = 0; q < 8; ++q) {                                         \
            int ks_ = q >> 2, m2_ = q & 3;                                    \
            int rr_ = m2_ * 16 + fr;                                          \
            unsigned off_ = abase_ + rr_ * 128                                \
                + ((unsigned)(ks_ * 64 + fg * 16) ^ (unsigned)((rr_ & 7) << 4)); \
            asm volatile("ds_read_b128 %0, %1" : "=&v"(AF[q]) : "v"(off_));   \
        }                                                                     \
        const bool hn_ = (ktv) + 1 < NKT;                                     \
        if (hn_) {                                                            \
            size_t ko_ = (size_t)((ktv) + 1) * 65536;                         \
            _Pragma("unroll")                                                 \
            for (int q = 0; q < 8; ++q) {                                     \
                int n2_ = q & 3, ks_ = q >> 2;                                \
                const void* a_ = pB[n2_] + ko_ + ks_ * 32768;                 \
                asm volatile("global_load_dwordx4 %0, %1, off"                \
                             : "=&v"(Bn[q]) : "v"(a_));                       \
            }                                                                 \
            int xo_ = ((ktv) + 2 < NKT) ? ((ktv) + 2) * 8 : 0;                \
            asm volatile("global_load_dword %0, %1, off"                      \
                         : "=&v"(xnext) : "v"((const void*)(xp + xo_)));      \
            asm volatile("s_waitcnt vmcnt(9)");                               \
        } else {                                                              \
            asm volatile("s_waitcnt vmcnt(0)");                               \
        }                                                                     \
        __builtin_amdgcn_sched_barrier(0);                                    \
        if (hn_) {                                                            \
            u32x4 w_ = kan_act(xcur);                                         \
            unsigned woff_ = asb + (cur_ ^ 1) * 8192 + ar * 128 + (c0 ^ as_sw); \
            asm volatile("ds_write_b128 %0, %1" :: "v"(woff_), "v"(w_));      \
            asm volatile("s_waitcnt lgkmcnt(1)");                             \
        } else {                                                              \
            asm volatile("s_waitcnt lgkmcnt(0)");                             \
        }                                                                     \
        __builtin_amdgcn_sched_barrier(0);                                    \
        _Pragma("unroll")                                                     \
        for (int ks_ = 0; ks_ < 2; ++ks_)                                     \
            _Pragma("unroll")                                                 \
            for (int m2_ = 0; m2_ < 4; ++m2_)                                 \
                _Pragma("unroll")                                             \
                for (int n2_ = 0; n2_ < 4; ++n2_)                             \
                    acc[m2_][n2_] = __builtin_amdgcn_mfma_f32_16x16x32_bf16(  \
                        AF[ks_ * 4 + m2_], Bc[ks_ * 4 + n2_], acc[m2_][n2_],  \
                        0, 0, 0);                                             \
        if (hn_) {                                                            \
            asm volatile("s_waitcnt lgkmcnt(0)");                             \
            __builtin_amdgcn_s_barrier();                                     \
        }                                                                     \
    }

    for (int kt = 0; kt < NKT; kt += 2) {
        STEP(kt,     Ba, Bb, xA, xB);
        STEP(kt + 1, Bb, Ba, xB, xA);
    }

    // ---- epilogue: C/D layout col = lane&15, row = (lane>>4)*4 + reg
    const int orow0 = row0 + fg * 4;
    const int ocol0 = wid * 64 + fr;
#pragma unroll
    for (int n2 = 0; n2 < 4; ++n2) {
        float bv = bias[ocol0 + n2 * 16];
#pragma unroll
        for (int m2 = 0; m2 < 4; ++m2) {
#pragma unroll
            for (int r = 0; r < 4; ++r) {
                y[(size_t)(orow0 + m2 * 16 + r) * DOUT + (ocol0 + n2 * 16)]
                    = acc[m2][n2][r] + bv;
            }
        }
    }
#undef STEP
}

extern "C" void kernel_launch(void* const* d_in, const int* in_sizes, int n_in,
                              void* d_out, int out_size, void* d_ws, size_t ws_size,
                              hipStream_t stream)
{
    const float* x          = (const float*)d_in[0];
    const float* coef       = (const float*)d_in[1];
    const float* scale_base = (const float*)d_in[2];
    const float* scale_sp   = (const float*)d_in[3];
    const float* bias       = (const float*)d_in[4];
    unsigned short* wt = (unsigned short*)d_ws;   // 4 MB packed wt[kt][ks][o][fg]
    float* y = (float*)d_out;

    kan_prep<<<1024, 256, 0, stream>>>(coef, scale_base, scale_sp, wt);
    kan_gemm<<<256, 512, 0, stream>>>(x, wt, bias, y);
}